// Round 1
// baseline (59.796 us; speedup 1.0000x reference)
//
#include <hip/hip_runtime.h>

#define N_CLASS_C 6

__global__ void zero_accum(float* accum) {
    if (threadIdx.x < N_CLASS_C) accum[threadIdx.x] = 0.0f;
}

__global__ void prep_atoms(const float* __restrict__ coords,
                           const float* __restrict__ radii,
                           const int* __restrict__ names,
                           float4* __restrict__ atoms,
                           int n_atoms) {
    int i = blockIdx.x * blockDim.x + threadIdx.x;
    if (i < n_atoms) {
        float4 a;
        a.x = coords[3 * i + 0];
        a.y = coords[3 * i + 1];
        a.z = coords[3 * i + 2];
        a.w = radii[names[i]];
        atoms[i] = a;
    }
}

// PACKED: gather from float4 atoms table in ws. !PACKED: gather raw inputs.
template <bool PACKED>
__global__ __launch_bounds__(256) void clash_main(
    const int* __restrict__ pairs,      // 2 * n_pairs
    const float4* __restrict__ atoms,   // n_atoms (PACKED only)
    const float* __restrict__ coords,   // 3 * n_atoms
    const float* __restrict__ radii,
    const int* __restrict__ names,
    const int* __restrict__ masks,      // N_CLASS * n_pairs
    const float* __restrict__ tol,      // N_CLASS
    float* __restrict__ accum,          // N_CLASS
    int n_pairs) {
    float tc[N_CLASS_C];
#pragma unroll
    for (int c = 0; c < N_CLASS_C; ++c) tc[c] = tol[c];
    float tmax = tc[0];
#pragma unroll
    for (int c = 1; c < N_CLASS_C; ++c) tmax = fmaxf(tmax, tc[c]);

    float s[N_CLASS_C];
#pragma unroll
    for (int c = 0; c < N_CLASS_C; ++c) s[c] = 0.0f;

    const int ngroups = n_pairs >> 2;
    const int gid = blockIdx.x * blockDim.x + threadIdx.x;
    const int stride = gridDim.x * blockDim.x;
    const int4* pairs4 = reinterpret_cast<const int4*>(pairs);

    for (int g = gid; g < ngroups; g += stride) {
        int4 pa = pairs4[2 * g];
        int4 pb = pairs4[2 * g + 1];
        int i0[4] = {pa.x, pa.z, pb.x, pb.z};
        int i1[4] = {pa.y, pa.w, pb.y, pb.w};
        float base[4];
#pragma unroll
        for (int j = 0; j < 4; ++j) {
            float ax, ay, az, ar, bx, by, bz, br;
            if (PACKED) {
                float4 A = atoms[i0[j]];
                float4 B = atoms[i1[j]];
                ax = A.x; ay = A.y; az = A.z; ar = A.w;
                bx = B.x; by = B.y; bz = B.z; br = B.w;
            } else {
                ax = coords[3 * i0[j] + 0];
                ay = coords[3 * i0[j] + 1];
                az = coords[3 * i0[j] + 2];
                ar = radii[names[i0[j]]];
                bx = coords[3 * i1[j] + 0];
                by = coords[3 * i1[j] + 1];
                bz = coords[3 * i1[j] + 2];
                br = radii[names[i1[j]]];
            }
            float dx = ax - bx, dy = ay - by, dz = az - bz;
            float dist = sqrtf(dx * dx + dy * dy + dz * dz + 1e-12f);
            base[j] = (ar + br) - dist;
        }
        float bm = fmaxf(fmaxf(base[0], base[1]), fmaxf(base[2], base[3]));
        // Masks only matter when some relu(base + tol) can be > 0.
        if (bm + tmax > 0.0f) {
#pragma unroll
            for (int c = 0; c < N_CLASS_C; ++c) {
                int4 m = reinterpret_cast<const int4*>(masks + (size_t)c * n_pairs)[g];
                float acc = 0.0f;
                if (m.x) acc += fmaxf(base[0] + tc[c], 0.0f);
                if (m.y) acc += fmaxf(base[1] + tc[c], 0.0f);
                if (m.z) acc += fmaxf(base[2] + tc[c], 0.0f);
                if (m.w) acc += fmaxf(base[3] + tc[c], 0.0f);
                s[c] += acc;
            }
        }
    }

    // Tail pairs (n_pairs not divisible by 4) — scalar path.
    for (int p = (ngroups << 2) + gid; p < n_pairs; p += stride) {
        int a0 = pairs[2 * p], a1 = pairs[2 * p + 1];
        float ax, ay, az, ar, bx, by, bz, br;
        if (PACKED) {
            float4 A = atoms[a0]; float4 B = atoms[a1];
            ax = A.x; ay = A.y; az = A.z; ar = A.w;
            bx = B.x; by = B.y; bz = B.z; br = B.w;
        } else {
            ax = coords[3 * a0]; ay = coords[3 * a0 + 1]; az = coords[3 * a0 + 2];
            ar = radii[names[a0]];
            bx = coords[3 * a1]; by = coords[3 * a1 + 1]; bz = coords[3 * a1 + 2];
            br = radii[names[a1]];
        }
        float dx = ax - bx, dy = ay - by, dz = az - bz;
        float dist = sqrtf(dx * dx + dy * dy + dz * dz + 1e-12f);
        float base = (ar + br) - dist;
        if (base + tmax > 0.0f) {
#pragma unroll
            for (int c = 0; c < N_CLASS_C; ++c) {
                if (masks[(size_t)c * n_pairs + p])
                    s[c] += fmaxf(base + tc[c], 0.0f);
            }
        }
    }

    __shared__ float sh[N_CLASS_C];
    if (threadIdx.x < N_CLASS_C) sh[threadIdx.x] = 0.0f;
    __syncthreads();
#pragma unroll
    for (int c = 0; c < N_CLASS_C; ++c) {
        float v = s[c];
#pragma unroll
        for (int off = 32; off > 0; off >>= 1) v += __shfl_down(v, off, 64);
        if ((threadIdx.x & 63) == 0) atomicAdd(&sh[c], v);
    }
    __syncthreads();
    if (threadIdx.x < N_CLASS_C) atomicAdd(&accum[threadIdx.x], sh[threadIdx.x]);
}

__global__ void finalize(const float* __restrict__ accum,
                         const float* __restrict__ w,
                         float* __restrict__ out) {
    int c = threadIdx.x;
    if (c < N_CLASS_C) {
        float scale = expf(w[0]);
        out[c] = accum[c] * scale;
    }
}

extern "C" void kernel_launch(void* const* d_in, const int* in_sizes, int n_in,
                              void* d_out, int out_size, void* d_ws, size_t ws_size,
                              hipStream_t stream) {
    const float* coords = (const float*)d_in[0];
    const float* radii  = (const float*)d_in[1];
    const float* tol    = (const float*)d_in[2];
    const float* weight = (const float*)d_in[3];
    const int* names    = (const int*)d_in[4];
    const int* pairs    = (const int*)d_in[5];
    const int* masks    = (const int*)d_in[6];
    float* out = (float*)d_out;

    int n_atoms = in_sizes[4];
    int n_pairs = in_sizes[5] / 2;

    size_t atoms_bytes = ((size_t)n_atoms * sizeof(float4) + 255) & ~(size_t)255;
    bool packed = ws_size >= atoms_bytes + 256;

    int blocks = 2048;

    if (packed) {
        float4* atoms = (float4*)d_ws;
        float* accum = (float*)((char*)d_ws + atoms_bytes);
        prep_atoms<<<(n_atoms + 255) / 256, 256, 0, stream>>>(coords, radii, names, atoms, n_atoms);
        zero_accum<<<1, 64, 0, stream>>>(accum);
        clash_main<true><<<blocks, 256, 0, stream>>>(pairs, atoms, coords, radii, names,
                                                     masks, tol, accum, n_pairs);
        finalize<<<1, 64, 0, stream>>>(accum, weight, out);
    } else {
        float* accum = out;  // accumulate raw sums in d_out, then scale in place
        zero_accum<<<1, 64, 0, stream>>>(accum);
        clash_main<false><<<blocks, 256, 0, stream>>>(pairs, nullptr, coords, radii, names,
                                                      masks, tol, accum, n_pairs);
        finalize<<<1, 64, 0, stream>>>(accum, weight, out);
    }
}